// Round 16
// baseline (282.226 us; speedup 1.0000x reference)
//
#include <hip/hip_runtime.h>
#include <hip/hip_bf16.h>
#include <cstdint>
#include <cstddef>

constexpr int C_  = 256;
constexpr int H_  = 224;
constexpr int W_  = 224;
constexpr int P_  = 49;
constexpr int M_  = 1024;
constexpr int HW_ = H_ * W_;

constexpr size_t IMG_ELEMS = (size_t)4 * C_ * H_ * W_;
constexpr size_t SCO_ELEMS = (size_t)4 * M_ * P_ * P_;
constexpr size_t OFF_SC  = IMG_ELEMS;
constexpr size_t OFF_COV = OFF_SC  + SCO_ELEMS;
constexpr size_t OFF_L   = OFF_COV + SCO_ELEMS;
constexpr size_t OFF_EC  = OFF_L   + SCO_ELEMS;

typedef __attribute__((ext_vector_type(8))) short short8;
typedef __attribute__((ext_vector_type(4))) float f32x4;

// Workspace: Ec wave-native packed, trimmed to valid tokens.
// Per (bm, wid): 1568 uints (6272B):
//   main [0,1536): idx = ((ct*3 + pt)*64 + lane)*2 + rp   (pt = 0..2, p<48)
//   tail [1536,1568): p=48 row: idx = 1536 + lh*8 + ct*2 + rp (l15==0 lanes)
constexpr size_t WSW_UINTS = 1568;                             // per wave
constexpr size_t WS_NEED   = (size_t)4096 * 4 * WSW_UINTS * 4; // 102,760,448 B

// K1 LDS map (47,488 B -> 3 blocks/CU):
constexpr int SA_OFF  = 0;        // 64 rows x 512B bf16 swizzled (49..63 = 0)
constexpr int GB_OFF  = 32768;    // 64 x 128B bf16 (G-u) -> Lb overlay (49..63 zeroed)
constexpr int SCB_OFF = 40960;    // 49 x 128B bf16 Sc
constexpr int U_OFF   = 47232;    // 64 f32
constexpr int SMEM_BYTES = 47488;

__device__ __forceinline__ int srowswz(int r) { return ((r ^ (r >> 3)) & 7) << 4; }

__device__ __forceinline__ short f2bf_s(float v) {
    __hip_bfloat16 b = __float2bfloat16(v);
    return *reinterpret_cast<short*>(&b);
}
__device__ __forceinline__ float bf2f_s(short s) {
    __hip_bfloat16 b = *reinterpret_cast<__hip_bfloat16*>(&s);
    return __bfloat162float(b);
}
__device__ __forceinline__ unsigned int packbf(float lo, float hi) {
    return (unsigned int)(unsigned short)f2bf_s(lo) |
           ((unsigned int)(unsigned short)f2bf_s(hi) << 16);
}

template<bool SPLIT>
__global__ __launch_bounds__(256, 3)
void psa_kernel(const float* __restrict__ x, const float* __restrict__ betap,
                float* __restrict__ out_img, float* __restrict__ out_sc,
                float* __restrict__ out_cov, float* __restrict__ out_l,
                float* __restrict__ out_ec,
                unsigned int* __restrict__ ws_ec)
{
    __shared__ __align__(16) unsigned char smem[SMEM_BYTES];
    float* uArr = (float*)(smem + U_OFF);

    const int tid = threadIdx.x;
    const int bid = blockIdx.x;
    const int bm  = ((bid & 7) << 9) | (bid >> 3);   // XCD-bijective swizzle
    const int b   = bm >> 10;
    const int m   = bm & (M_ - 1);
    const int mh  = m >> 5;
    const int mw  = m & 31;
    const float beta = betap[0];
    const size_t xpatch = (((size_t)b * C_ * H_) + (size_t)mh * 7) * W_ + (size_t)mw * 7;

    const int wid = tid >> 6, lane = tid & 63, l15 = lane & 15, lh = lane >> 4;

    // ---- Phase 0: stage x -> sA (lane = token, 8ch per ds_write_b128) ----
    {
        const int p = lane;
        const int i = p / 7, j = p - 7 * (p / 7);
        const float* xp = x + xpatch + (size_t)i * W_ + j + (size_t)(64 * wid) * HW_;
        const int swzp = srowswz(p);
        unsigned char* sbase = smem + SA_OFF + p * 512 + 128 * wid;
        #pragma unroll
        for (int g = 0; g < 8; ++g) {
            short8 pk;
            if (p < P_) {
                #pragma unroll
                for (int k = 0; k < 8; ++k)
                    pk[k] = f2bf_s(xp[(size_t)(8 * g + k) * HW_]);
            } else {
                pk = short8{0, 0, 0, 0, 0, 0, 0, 0};
            }
            *(short8*)(sbase + ((16 * g) ^ swzp)) = pk;
        }
    }
    __syncthreads();

    // ---- Phase 1: G = A A^T (MFMA, K=256); G stays in registers ----
    f32x4 gacc[4] = {f32x4{0,0,0,0}, f32x4{0,0,0,0}, f32x4{0,0,0,0}, f32x4{0,0,0,0}};
    {
        const int arow = 16 * wid + l15;
        #pragma unroll
        for (int kc = 0; kc < 8; ++kc) {
            const int cb = 64 * kc + 16 * lh;
            const short8 af = *(const short8*)(smem + SA_OFF + arow * 512 + (cb ^ srowswz(arow)));
            #pragma unroll
            for (int t = 0; t < 4; ++t) {
                const int brow = 16 * t + l15;
                const short8 bf = *(const short8*)(smem + SA_OFF + brow * 512 + (cb ^ srowswz(brow)));
                gacc[t] = __builtin_amdgcn_mfma_f32_16x16x32_bf16(af, bf, gacc[t], 0, 0, 0);
            }
        }
    }

    // ---- Phase 2: in-register row stats; u = rowmean (G symmetric) ----
    float mx[4];
    {
        #pragma unroll
        for (int r = 0; r < 4; ++r) {
            const int p = 16 * wid + 4 * lh + r;
            float m_ = fmaxf(fmaxf(gacc[0][r], gacc[1][r]), gacc[2][r]);
            m_ = fmaxf(m_, (l15 == 0) ? gacc[3][r] : -3.4e38f);
            float s_ = gacc[0][r] + gacc[1][r] + gacc[2][r] + ((l15 == 0) ? gacc[3][r] : 0.f);
            #pragma unroll
            for (int d = 1; d < 16; d <<= 1) {
                m_ = fmaxf(m_, __shfl_xor(m_, d));
                s_ += __shfl_xor(s_, d);
            }
            mx[r] = m_;
            if (l15 == 0 && p <= 48) uArr[p] = s_ * (1.f / 49.f);
        }
    }
    __syncthreads();

    // ---- Phase 3: Gb = bf16(G-u); in-reg exp/rowsum/scale; Scb; Sc global
    // written DIRECTLY from registers (fp32, 64B lane-runs). ----
    float sc[4][4];
    {
        for (int s = tid; s < 120; s += 256)
            *(short8*)(smem + GB_OFF + 49 * 128 + s * 16) = short8{0,0,0,0,0,0,0,0};
        float* sc_g = out_sc + (size_t)bm * (P_ * P_);
        #pragma unroll
        for (int r = 0; r < 4; ++r) {
            const int p = 16 * wid + 4 * lh + r;
            if (p <= 48) {
                #pragma unroll
                for (int t = 0; t < 4; ++t) {
                    const int qv = 16 * t + l15;
                    const float gv = (qv <= 48) ? (gacc[t][r] - uArr[qv]) : 0.f;
                    *(__hip_bfloat16*)(smem + GB_OFF + p * 128 + ((2 * qv) ^ srowswz(p))) =
                        __float2bfloat16(gv);
                }
            }
            float e[4];
            #pragma unroll
            for (int t = 0; t < 4; ++t) {
                const int qv = 16 * t + l15;
                e[t] = (qv <= 48) ? __expf(gacc[t][r] - mx[r]) : 0.f;
            }
            float s_ = e[0] + e[1] + e[2] + e[3];
            #pragma unroll
            for (int d = 1; d < 16; d <<= 1) s_ += __shfl_xor(s_, d);
            const float rinv = 1.f / s_;
            #pragma unroll
            for (int t = 0; t < 4; ++t) sc[t][r] = e[t] * rinv;
            if (p <= 48) {
                #pragma unroll
                for (int t = 0; t < 4; ++t) {
                    const int qv = 16 * t + l15;
                    *(__hip_bfloat16*)(smem + SCB_OFF + p * 128 + ((2 * qv) ^ srowswz(p))) =
                        __float2bfloat16(sc[t][r]);
                    if (qv <= 48) sc_g[p * 49 + qv] = sc[t][r];
                }
            }
        }
    }
    __syncthreads();

    // ---- Phase 4: cov MFMA: cacc = Gb . Scb^T (K=64); T2 = rowmean in-reg ----
    f32x4 cacc[4] = {f32x4{0,0,0,0}, f32x4{0,0,0,0}, f32x4{0,0,0,0}, f32x4{0,0,0,0}};
    {
        const int arow = 16 * wid + l15;
        #pragma unroll
        for (int kc = 0; kc < 2; ++kc) {
            const int cb = 64 * kc + 16 * lh;
            const short8 af = *(const short8*)(smem + GB_OFF + arow * 128 + (cb ^ srowswz(arow)));
            #pragma unroll
            for (int t = 0; t < 4; ++t) {
                const int brow = 16 * t + l15;
                const short8 bf = *(const short8*)(smem + SCB_OFF + brow * 128 + (cb ^ srowswz(brow)));
                cacc[t] = __builtin_amdgcn_mfma_f32_16x16x32_bf16(af, bf, cacc[t], 0, 0, 0);
            }
        }
    }
    float t2[4];
    {
        #pragma unroll
        for (int r = 0; r < 4; ++r) {
            float s_ = cacc[0][r] + cacc[1][r] + cacc[2][r] + ((l15 == 0) ? cacc[3][r] : 0.f);
            #pragma unroll
            for (int d = 1; d < 16; d <<= 1) s_ += __shfl_xor(s_, d);
            t2[r] = s_ * (1.f / 49.f);
        }
    }
    __syncthreads();

    // ---- Phase 5: cv = (cacc - T2)/49; L = Sc + cv; cov/L global from
    // registers (fp32); Lb LDS write ----
    {
        float* cov_g = out_cov + (size_t)bm * (P_ * P_);
        float* l_g   = out_l   + (size_t)bm * (P_ * P_);
        #pragma unroll
        for (int t = 0; t < 4; ++t) {
            const int qv = 16 * t + l15;
            #pragma unroll
            for (int r = 0; r < 4; ++r) {
                const int p = 16 * wid + 4 * lh + r;
                if (p <= 48 && qv <= 48) {
                    const float cv = (cacc[t][r] - t2[r]) * (1.f / 49.f);
                    const float lv = sc[t][r] + cv;
                    cov_g[p * 49 + qv] = cv;
                    l_g  [p * 49 + qv] = lv;
                    *(__hip_bfloat16*)(smem + GB_OFF + p * 128 + ((2 * qv) ^ srowswz(p))) =
                        __float2bfloat16(lv);
                }
            }
        }
    }
    __syncthreads();

    // ---- Phase 6: Ec^T = A^T . L^T (D[c][p]); wave wid -> c in [64wid, +64) ----
    {
        f32x4 acc[4][4];   // [ct][pt]
        #pragma unroll
        for (int i = 0; i < 4; ++i)
            #pragma unroll
            for (int j2 = 0; j2 < 4; ++j2) acc[i][j2] = f32x4{0, 0, 0, 0};

        #pragma unroll
        for (int kc = 0; kc < 2; ++kc) {
            const int cb = 64 * kc + 16 * lh;
            short8 bf[4];
            #pragma unroll
            for (int pt = 0; pt < 4; ++pt) {
                const int brow = 16 * pt + l15;
                bf[pt] = *(const short8*)(smem + GB_OFF + brow * 128 + (cb ^ srowswz(brow)));
            }
            #pragma unroll
            for (int ct = 0; ct < 4; ++ct) {
                const int c = 64 * wid + 16 * ct + l15;
                short8 af;
                #pragma unroll
                for (int j = 0; j < 8; ++j) {
                    const int q2 = 32 * kc + 8 * lh + j;
                    af[j] = *(const short*)(smem + SA_OFF + q2 * 512 + ((2 * c) ^ srowswz(q2)));
                }
                #pragma unroll
                for (int pt = 0; pt < 4; ++pt)
                    acc[ct][pt] = __builtin_amdgcn_mfma_f32_16x16x32_bf16(af, bf[pt], acc[ct][pt], 0, 0, 0);
            }
        }

        if (SPLIT) {
            // Trimmed wave-native ws: 12 uint2 stores (512B/instr) + p=48 tail.
            unsigned int* wec = ws_ec + ((size_t)bm * 4 + wid) * WSW_UINTS;
            #pragma unroll
            for (int ct = 0; ct < 4; ++ct) {
                #pragma unroll
                for (int pt = 0; pt < 3; ++pt) {
                    uint2 v;
                    v.x = packbf(acc[ct][pt][0], acc[ct][pt][1]);
                    v.y = packbf(acc[ct][pt][2], acc[ct][pt][3]);
                    *(uint2*)&wec[((ct * 3 + pt) * 64 + lane) * 2] = v;
                }
            }
            if (l15 == 0) {   // p = 48 row (pt == 3, l15 == 0 only valid)
                #pragma unroll
                for (int ct = 0; ct < 4; ++ct)
                    #pragma unroll
                    for (int rp = 0; rp < 2; ++rp)
                        wec[1536 + lh * 8 + ct * 2 + rp] =
                            packbf(acc[ct][3][2 * rp], acc[ct][3][2 * rp + 1]);
            }
        } else {
            #pragma unroll
            for (int pt = 0; pt < 4; ++pt) {
                const int p = 16 * pt + l15;
                if (p > 48) continue;
                const int i = p / 7, j = p - 7 * (p / 7);
                const size_t base = xpatch + (size_t)i * W_ + j;
                #pragma unroll
                for (int ct = 0; ct < 4; ++ct) {
                    #pragma unroll
                    for (int r = 0; r < 4; ++r) {
                        const int c = 64 * wid + 16 * ct + 4 * lh + r;
                        const size_t g = base + (size_t)c * HW_;
                        const float ec = acc[ct][pt][r];
                        const float xv = bf2f_s(*(const short*)(smem + SA_OFF + p * 512 + ((2 * c) ^ srowswz(p))));
                        out_ec [g] = ec;
                        out_img[g] = xv * fmaf(beta, ec, xv);
                    }
                }
            }
        }
    }
}

// Fold: block = (b, c-quad, mh). The 4 staged channels share (widc,ctc,lhc)
// and differ only in (rp, half) -> each uint pair feeds all 4 channels.
__global__ __launch_bounds__(256)
void fold_kernel(const unsigned int* __restrict__ ws_ec,
                 const float* __restrict__ x, const float* __restrict__ betap,
                 float* __restrict__ out_img, float* __restrict__ out_ec)
{
    __shared__ short lec[4][32][64];   // [rc][patch][p]; 16,384 B

    const int bid = blockIdx.x;
    const int mh  = bid & 31;
    const int bcg = bid >> 5;          // b*64 + cgroup
    const int b   = bcg >> 6;
    const int c0  = (bcg & 63) << 2;
    const int t   = threadIdx.x;
    const float beta = betap[0];

    const int widc = c0 >> 6;
    const int ctc  = (c0 >> 4) & 3;
    const int lhc  = (c0 >> 2) & 3;

    // Stage main: k(32) x pt(3) x l15(16) x rp(2) = 3072 uint loads.
    for (int s = t; s < 3072; s += 256) {
        const int k   = s / 96;
        const int rem = s - k * 96;       // pt*32 + l15*2 + rp
        const int pt  = rem >> 5;
        const int l15 = (rem >> 1) & 15;
        const int rp  = rem & 1;
        const size_t bm = (size_t)(b << 10) + (mh << 5) + k;
        const unsigned int v = ws_ec[(bm * 4 + widc) * WSW_UINTS +
                                     ((ctc * 3 + pt) * 64 + lhc * 16 + l15) * 2 + rp];
        const int p = pt * 16 + l15;
        lec[2 * rp]    [k][p] = (short)(v & 0xFFFF);
        lec[2 * rp + 1][k][p] = (short)(v >> 16);
    }
    // Stage tail p=48: k(32) x rp(2) = 64 loads.
    for (int s = t; s < 64; s += 256) {
        const int k = s >> 1, rp = s & 1;
        const size_t bm = (size_t)(b << 10) + (mh << 5) + k;
        const unsigned int v = ws_ec[(bm * 4 + widc) * WSW_UINTS + 1536 +
                                     lhc * 8 + ctc * 2 + rp];
        lec[2 * rp]    [k][48] = (short)(v & 0xFFFF);
        lec[2 * rp + 1][k][48] = (short)(v >> 16);
    }
    __syncthreads();

    // Emit: 4 channels x 7 rows x 56 float4s = 1568 iterations (full lines).
    for (int idx = t; idx < 1568; idx += 256) {
        const int cc = idx / 392;
        const int r2 = idx - cc * 392;
        const int i  = r2 / 56;
        const int w0 = (r2 - i * 56) * 4;
        const size_t g = (((size_t)(b * C_ + c0 + cc)) * H_ + (size_t)mh * 7 + i) * W_ + w0;
        const float4 xv = *(const float4*)&x[g];
        float4 vo, ve;
        #pragma unroll
        for (int e = 0; e < 4; ++e) {
            const int w  = w0 + e;
            const int mw = w / 7;
            const int p  = i * 7 + (w - mw * 7);
            const float ec = bf2f_s(lec[cc][mw][p]);
            const float xe = ((const float*)&xv)[e];
            ((float*)&ve)[e] = ec;
            ((float*)&vo)[e] = xe * fmaf(beta, ec, xe);
        }
        *(float4*)&out_ec [g] = ve;
        *(float4*)&out_img[g] = vo;
    }
}

extern "C" void kernel_launch(void* const* d_in, const int* in_sizes, int n_in,
                              void* d_out, int out_size, void* d_ws, size_t ws_size,
                              hipStream_t stream) {
    const float* x    = (const float*)d_in[0];
    const float* beta = (const float*)d_in[1];
    float* out = (float*)d_out;

    if (ws_size >= WS_NEED) {
        unsigned int* ws_ec = (unsigned int*)d_ws;
        psa_kernel<true><<<dim3(4 * M_), dim3(256), 0, stream>>>(
            x, beta, out, out + OFF_SC, out + OFF_COV, out + OFF_L, out + OFF_EC,
            ws_ec);
        fold_kernel<<<dim3(8192), dim3(256), 0, stream>>>(
            ws_ec, x, beta, out, out + OFF_EC);
    } else {
        psa_kernel<false><<<dim3(4 * M_), dim3(256), 0, stream>>>(
            x, beta, out, out + OFF_SC, out + OFF_COV, out + OFF_L, out + OFF_EC,
            nullptr);
    }
}

// Round 17
// 266.532 us; speedup vs baseline: 1.0589x; 1.0589x over previous
//
#include <hip/hip_runtime.h>
#include <hip/hip_bf16.h>
#include <cstdint>
#include <cstddef>

constexpr int C_  = 256;
constexpr int H_  = 224;
constexpr int W_  = 224;
constexpr int P_  = 49;
constexpr int M_  = 1024;
constexpr int HW_ = H_ * W_;

constexpr size_t IMG_ELEMS = (size_t)4 * C_ * H_ * W_;
constexpr size_t SCO_ELEMS = (size_t)4 * M_ * P_ * P_;
constexpr size_t OFF_SC  = IMG_ELEMS;
constexpr size_t OFF_COV = OFF_SC  + SCO_ELEMS;
constexpr size_t OFF_L   = OFF_COV + SCO_ELEMS;
constexpr size_t OFF_EC  = OFF_L   + SCO_ELEMS;

typedef __attribute__((ext_vector_type(8))) short short8;
typedef __attribute__((ext_vector_type(4))) float f32x4;

// Workspace: Ec wave-native packed, TRIMMED to valid tokens.
// Per (bm, wid): 1568 uints (6272B):
//   main [0,1536): idx = ((ct*3 + pt)*64 + lane)*2 + rp   (pt = 0..2, p<48)
//     uint = pack(bf16 Ec[c_lo], bf16 Ec[c_hi]), c = 64wid+16ct+4lh+2rp(+hi)
//   tail [1536,1568): p=48 row: idx = 1536 + lh*8 + ct*2 + rp (l15==0 lanes)
// psa stores: 12 x uint2 (512B/wave-instr) + 8 predicated tail stores.
constexpr size_t WSW_UINTS = 1568;                             // per wave
constexpr size_t WS_NEED   = (size_t)4096 * 4 * WSW_UINTS * 4; // 102,760,448 B

// K1 LDS map (47,488 B -> 3 blocks/CU):
constexpr int SA_OFF  = 0;        // 64 rows x 512B bf16 swizzled (49..63 = 0)
constexpr int GB_OFF  = 32768;    // 64 x 128B bf16 (G-u) -> Lb overlay (49..63 zeroed)
constexpr int SCB_OFF = 40960;    // 49 x 128B bf16 Sc
constexpr int U_OFF   = 47232;    // 64 f32
constexpr int SMEM_BYTES = 47488;

__device__ __forceinline__ int srowswz(int r) { return ((r ^ (r >> 3)) & 7) << 4; }

__device__ __forceinline__ short f2bf_s(float v) {
    __hip_bfloat16 b = __float2bfloat16(v);
    return *reinterpret_cast<short*>(&b);
}
__device__ __forceinline__ float bf2f_s(short s) {
    __hip_bfloat16 b = *reinterpret_cast<__hip_bfloat16*>(&s);
    return __bfloat162float(b);
}
__device__ __forceinline__ unsigned int packbf(float lo, float hi) {
    return (unsigned int)(unsigned short)f2bf_s(lo) |
           ((unsigned int)(unsigned short)f2bf_s(hi) << 16);
}

template<bool SPLIT>
__global__ __launch_bounds__(256, 3)
void psa_kernel(const float* __restrict__ x, const float* __restrict__ betap,
                float* __restrict__ out_img, float* __restrict__ out_sc,
                float* __restrict__ out_cov, float* __restrict__ out_l,
                float* __restrict__ out_ec,
                unsigned int* __restrict__ ws_ec)
{
    __shared__ __align__(16) unsigned char smem[SMEM_BYTES];
    float* uArr = (float*)(smem + U_OFF);

    const int tid = threadIdx.x;
    const int bid = blockIdx.x;
    const int bm  = ((bid & 7) << 9) | (bid >> 3);   // XCD-bijective swizzle
    const int b   = bm >> 10;
    const int m   = bm & (M_ - 1);
    const int mh  = m >> 5;
    const int mw  = m & 31;
    const float beta = betap[0];
    const size_t xpatch = (((size_t)b * C_ * H_) + (size_t)mh * 7) * W_ + (size_t)mw * 7;

    const int wid = tid >> 6, lane = tid & 63, l15 = lane & 15, lh = lane >> 4;

    // ---- Phase 0: stage x -> sA (lane = token, 8ch per ds_write_b128) ----
    {
        const int p = lane;
        const int i = p / 7, j = p - 7 * (p / 7);
        const float* xp = x + xpatch + (size_t)i * W_ + j + (size_t)(64 * wid) * HW_;
        const int swzp = srowswz(p);
        unsigned char* sbase = smem + SA_OFF + p * 512 + 128 * wid;
        #pragma unroll
        for (int g = 0; g < 8; ++g) {
            short8 pk;
            if (p < P_) {
                #pragma unroll
                for (int k = 0; k < 8; ++k)
                    pk[k] = f2bf_s(xp[(size_t)(8 * g + k) * HW_]);
            } else {
                pk = short8{0, 0, 0, 0, 0, 0, 0, 0};
            }
            *(short8*)(sbase + ((16 * g) ^ swzp)) = pk;
        }
    }
    __syncthreads();

    // ---- Phase 1: G = A A^T (MFMA, K=256); G stays in registers ----
    f32x4 gacc[4] = {f32x4{0,0,0,0}, f32x4{0,0,0,0}, f32x4{0,0,0,0}, f32x4{0,0,0,0}};
    {
        const int arow = 16 * wid + l15;
        #pragma unroll
        for (int kc = 0; kc < 8; ++kc) {
            const int cb = 64 * kc + 16 * lh;
            const short8 af = *(const short8*)(smem + SA_OFF + arow * 512 + (cb ^ srowswz(arow)));
            #pragma unroll
            for (int t = 0; t < 4; ++t) {
                const int brow = 16 * t + l15;
                const short8 bf = *(const short8*)(smem + SA_OFF + brow * 512 + (cb ^ srowswz(brow)));
                gacc[t] = __builtin_amdgcn_mfma_f32_16x16x32_bf16(af, bf, gacc[t], 0, 0, 0);
            }
        }
    }

    // ---- Phase 2: in-register row stats; u = rowmean (G symmetric) ----
    float mx[4];
    {
        #pragma unroll
        for (int r = 0; r < 4; ++r) {
            const int p = 16 * wid + 4 * lh + r;
            float m_ = fmaxf(fmaxf(gacc[0][r], gacc[1][r]), gacc[2][r]);
            m_ = fmaxf(m_, (l15 == 0) ? gacc[3][r] : -3.4e38f);
            float s_ = gacc[0][r] + gacc[1][r] + gacc[2][r] + ((l15 == 0) ? gacc[3][r] : 0.f);
            #pragma unroll
            for (int d = 1; d < 16; d <<= 1) {
                m_ = fmaxf(m_, __shfl_xor(m_, d));
                s_ += __shfl_xor(s_, d);
            }
            mx[r] = m_;
            if (l15 == 0 && p <= 48) uArr[p] = s_ * (1.f / 49.f);
        }
    }
    __syncthreads();

    // ---- Phase 3: Gb = bf16(G-u); in-reg exp/rowsum/scale; Scb.
    // Also zero Gb rows 49..63 (read by phase 6's B-fragments). ----
    float sc[4][4];
    {
        for (int s = tid; s < 120; s += 256)
            *(short8*)(smem + GB_OFF + 49 * 128 + s * 16) = short8{0,0,0,0,0,0,0,0};
        #pragma unroll
        for (int r = 0; r < 4; ++r) {
            const int p = 16 * wid + 4 * lh + r;
            if (p <= 48) {
                #pragma unroll
                for (int t = 0; t < 4; ++t) {
                    const int qv = 16 * t + l15;
                    const float gv = (qv <= 48) ? (gacc[t][r] - uArr[qv]) : 0.f;
                    *(__hip_bfloat16*)(smem + GB_OFF + p * 128 + ((2 * qv) ^ srowswz(p))) =
                        __float2bfloat16(gv);
                }
            }
            float e[4];
            #pragma unroll
            for (int t = 0; t < 4; ++t) {
                const int qv = 16 * t + l15;
                e[t] = (qv <= 48) ? __expf(gacc[t][r] - mx[r]) : 0.f;
            }
            float s_ = e[0] + e[1] + e[2] + e[3];
            #pragma unroll
            for (int d = 1; d < 16; d <<= 1) s_ += __shfl_xor(s_, d);
            const float rinv = 1.f / s_;
            #pragma unroll
            for (int t = 0; t < 4; ++t) sc[t][r] = e[t] * rinv;
            if (p <= 48) {
                #pragma unroll
                for (int t = 0; t < 4; ++t) {
                    const int qv = 16 * t + l15;
                    *(__hip_bfloat16*)(smem + SCB_OFF + p * 128 + ((2 * qv) ^ srowswz(p))) =
                        __float2bfloat16(sc[t][r]);
                    if (!SPLIT && qv <= 48)
                        out_sc[(size_t)bm * (P_ * P_) + p * 49 + qv] = sc[t][r];
                }
            }
        }
    }
    __syncthreads();

    // ---- Phase 4: cov MFMA: cacc = Gb . Scb^T (K=64); T2 = rowmean in-reg ----
    f32x4 cacc[4] = {f32x4{0,0,0,0}, f32x4{0,0,0,0}, f32x4{0,0,0,0}, f32x4{0,0,0,0}};
    {
        const int arow = 16 * wid + l15;
        #pragma unroll
        for (int kc = 0; kc < 2; ++kc) {
            const int cb = 64 * kc + 16 * lh;
            const short8 af = *(const short8*)(smem + GB_OFF + arow * 128 + (cb ^ srowswz(arow)));
            #pragma unroll
            for (int t = 0; t < 4; ++t) {
                const int brow = 16 * t + l15;
                const short8 bf = *(const short8*)(smem + SCB_OFF + brow * 128 + (cb ^ srowswz(brow)));
                cacc[t] = __builtin_amdgcn_mfma_f32_16x16x32_bf16(af, bf, cacc[t], 0, 0, 0);
            }
        }
    }
    float t2[4];
    {
        #pragma unroll
        for (int r = 0; r < 4; ++r) {
            float s_ = cacc[0][r] + cacc[1][r] + cacc[2][r] + ((l15 == 0) ? cacc[3][r] : 0.f);
            #pragma unroll
            for (int d = 1; d < 16; d <<= 1) s_ += __shfl_xor(s_, d);
            t2[r] = s_ * (1.f / 49.f);
        }
    }
    __syncthreads();

    // ---- Phase 5: cv = (cacc - T2)/49; L = Sc + cv; Lb LDS write ----
    {
        #pragma unroll
        for (int t = 0; t < 4; ++t) {
            const int qv = 16 * t + l15;
            #pragma unroll
            for (int r = 0; r < 4; ++r) {
                const int p = 16 * wid + 4 * lh + r;
                if (p <= 48 && qv <= 48) {
                    const float cv = (cacc[t][r] - t2[r]) * (1.f / 49.f);
                    const float lv = sc[t][r] + cv;
                    if (!SPLIT) {
                        out_cov[(size_t)bm * (P_ * P_) + p * 49 + qv] = cv;
                        out_l  [(size_t)bm * (P_ * P_) + p * 49 + qv] = lv;
                    }
                    *(__hip_bfloat16*)(smem + GB_OFF + p * 128 + ((2 * qv) ^ srowswz(p))) =
                        __float2bfloat16(lv);
                }
            }
        }
    }
    __syncthreads();

    // ---- Phase 6: Ec^T = A^T . L^T (D[c][p]); wave wid -> c in [64wid, +64) ----
    {
        f32x4 acc[4][4];   // [ct][pt]
        #pragma unroll
        for (int i = 0; i < 4; ++i)
            #pragma unroll
            for (int j2 = 0; j2 < 4; ++j2) acc[i][j2] = f32x4{0, 0, 0, 0};

        #pragma unroll
        for (int kc = 0; kc < 2; ++kc) {
            const int cb = 64 * kc + 16 * lh;
            short8 bf[4];
            #pragma unroll
            for (int pt = 0; pt < 4; ++pt) {
                const int brow = 16 * pt + l15;
                bf[pt] = *(const short8*)(smem + GB_OFF + brow * 128 + (cb ^ srowswz(brow)));
            }
            #pragma unroll
            for (int ct = 0; ct < 4; ++ct) {
                const int c = 64 * wid + 16 * ct + l15;
                short8 af;
                #pragma unroll
                for (int j = 0; j < 8; ++j) {
                    const int q2 = 32 * kc + 8 * lh + j;
                    af[j] = *(const short*)(smem + SA_OFF + q2 * 512 + ((2 * c) ^ srowswz(q2)));
                }
                #pragma unroll
                for (int pt = 0; pt < 4; ++pt)
                    acc[ct][pt] = __builtin_amdgcn_mfma_f32_16x16x32_bf16(af, bf[pt], acc[ct][pt], 0, 0, 0);
            }
        }

        if (SPLIT) {
            // Trimmed wave-native ws: 12 uint2 stores (512B/instr) + p=48 tail.
            unsigned int* wec = ws_ec + ((size_t)bm * 4 + wid) * WSW_UINTS;
            #pragma unroll
            for (int ct = 0; ct < 4; ++ct) {
                #pragma unroll
                for (int pt = 0; pt < 3; ++pt) {
                    uint2 v;
                    v.x = packbf(acc[ct][pt][0], acc[ct][pt][1]);
                    v.y = packbf(acc[ct][pt][2], acc[ct][pt][3]);
                    *(uint2*)&wec[((ct * 3 + pt) * 64 + lane) * 2] = v;
                }
            }
            if (l15 == 0) {   // p = 48 row (pt == 3, l15 == 0 only valid)
                #pragma unroll
                for (int ct = 0; ct < 4; ++ct)
                    #pragma unroll
                    for (int rp = 0; rp < 2; ++rp)
                        wec[1536 + lh * 8 + ct * 2 + rp] =
                            packbf(acc[ct][3][2 * rp], acc[ct][3][2 * rp + 1]);
            }
            // Deferred fp32 Sc/cov/L outputs (bf16-rounded; rel err ~0.4%).
            float* sc_g  = out_sc  + (size_t)bm * (P_ * P_);
            float* cov_g = out_cov + (size_t)bm * (P_ * P_);
            float* l_g   = out_l   + (size_t)bm * (P_ * P_);
            for (int e = tid; e < P_ * P_; e += 256) {
                const int p = e / 49, q = e - 49 * p;
                const float scv = bf2f_s(*(const short*)(smem + SCB_OFF + p * 128 + ((2 * q) ^ srowswz(p))));
                const float lvv = bf2f_s(*(const short*)(smem + GB_OFF  + p * 128 + ((2 * q) ^ srowswz(p))));
                sc_g[e]  = scv;
                l_g[e]   = lvv;
                cov_g[e] = lvv - scv;
            }
        } else {
            #pragma unroll
            for (int pt = 0; pt < 4; ++pt) {
                const int p = 16 * pt + l15;
                if (p > 48) continue;
                const int i = p / 7, j = p - 7 * (p / 7);
                const size_t base = xpatch + (size_t)i * W_ + j;
                #pragma unroll
                for (int ct = 0; ct < 4; ++ct) {
                    #pragma unroll
                    for (int r = 0; r < 4; ++r) {
                        const int c = 64 * wid + 16 * ct + 4 * lh + r;
                        const size_t g = base + (size_t)c * HW_;
                        const float ec = acc[ct][pt][r];
                        const float xv = bf2f_s(*(const short*)(smem + SA_OFF + p * 512 + ((2 * c) ^ srowswz(p))));
                        out_ec [g] = ec;
                        out_img[g] = xv * fmaf(beta, ec, xv);
                    }
                }
            }
        }
    }
}

// Fold: block = (b, c-quad, mh). The 4 staged channels share (widc,ctc,lhc)
// and differ only in (rp, half) -> each uint pair feeds all 4 channels.
__global__ __launch_bounds__(256)
void fold_kernel(const unsigned int* __restrict__ ws_ec,
                 const float* __restrict__ x, const float* __restrict__ betap,
                 float* __restrict__ out_img, float* __restrict__ out_ec)
{
    __shared__ short lec[4][32][64];   // [rc][patch][p]; 16,384 B

    const int bid = blockIdx.x;
    const int mh  = bid & 31;
    const int bcg = bid >> 5;          // b*64 + cgroup
    const int b   = bcg >> 6;
    const int c0  = (bcg & 63) << 2;
    const int t   = threadIdx.x;
    const float beta = betap[0];

    const int widc = c0 >> 6;
    const int ctc  = (c0 >> 4) & 3;
    const int lhc  = (c0 >> 2) & 3;

    // Stage main: k(32) x pt(3) x l15(16) x rp(2) = 3072 uint loads
    // (consecutive threads -> consecutive uints, 128B runs).
    for (int s = t; s < 3072; s += 256) {
        const int k   = s / 96;
        const int rem = s - k * 96;       // pt*32 + l15*2 + rp
        const int pt  = rem >> 5;
        const int l15 = (rem >> 1) & 15;
        const int rp  = rem & 1;
        const size_t bm = (size_t)(b << 10) + (mh << 5) + k;
        const unsigned int v = ws_ec[(bm * 4 + widc) * WSW_UINTS +
                                     ((ctc * 3 + pt) * 64 + lhc * 16 + l15) * 2 + rp];
        const int p = pt * 16 + l15;
        lec[2 * rp]    [k][p] = (short)(v & 0xFFFF);
        lec[2 * rp + 1][k][p] = (short)(v >> 16);
    }
    // Stage tail p=48: k(32) x rp(2) = 64 loads.
    for (int s = t; s < 64; s += 256) {
        const int k = s >> 1, rp = s & 1;
        const size_t bm = (size_t)(b << 10) + (mh << 5) + k;
        const unsigned int v = ws_ec[(bm * 4 + widc) * WSW_UINTS + 1536 +
                                     lhc * 8 + ctc * 2 + rp];
        lec[2 * rp]    [k][48] = (short)(v & 0xFFFF);
        lec[2 * rp + 1][k][48] = (short)(v >> 16);
    }
    __syncthreads();

    // Emit: 4 channels x 7 rows x 56 float4s = 1568 iterations (full lines).
    for (int idx = t; idx < 1568; idx += 256) {
        const int cc = idx / 392;
        const int r2 = idx - cc * 392;
        const int i  = r2 / 56;
        const int w0 = (r2 - i * 56) * 4;
        const size_t g = (((size_t)(b * C_ + c0 + cc)) * H_ + (size_t)mh * 7 + i) * W_ + w0;
        const float4 xv = *(const float4*)&x[g];
        float4 vo, ve;
        #pragma unroll
        for (int e = 0; e < 4; ++e) {
            const int w  = w0 + e;
            const int mw = w / 7;
            const int p  = i * 7 + (w - mw * 7);
            const float ec = bf2f_s(lec[cc][mw][p]);
            const float xe = ((const float*)&xv)[e];
            ((float*)&ve)[e] = ec;
            ((float*)&vo)[e] = xe * fmaf(beta, ec, xe);
        }
        *(float4*)&out_ec [g] = ve;
        *(float4*)&out_img[g] = vo;
    }
}

extern "C" void kernel_launch(void* const* d_in, const int* in_sizes, int n_in,
                              void* d_out, int out_size, void* d_ws, size_t ws_size,
                              hipStream_t stream) {
    const float* x    = (const float*)d_in[0];
    const float* beta = (const float*)d_in[1];
    float* out = (float*)d_out;

    if (ws_size >= WS_NEED) {
        unsigned int* ws_ec = (unsigned int*)d_ws;
        psa_kernel<true><<<dim3(4 * M_), dim3(256), 0, stream>>>(
            x, beta, out, out + OFF_SC, out + OFF_COV, out + OFF_L, out + OFF_EC,
            ws_ec);
        fold_kernel<<<dim3(8192), dim3(256), 0, stream>>>(
            ws_ec, x, beta, out, out + OFF_EC);
    } else {
        psa_kernel<false><<<dim3(4 * M_), dim3(256), 0, stream>>>(
            x, beta, out, out + OFF_SC, out + OFF_COV, out + OFF_L, out + OFF_EC,
            nullptr);
    }
}